// Round 5
// baseline (925.231 us; speedup 1.0000x reference)
//
#include <hip/hip_runtime.h>

#define D_MODEL 1024
#define D_FF    4096
#define N_HEADS 16
#define DK      64
#define BATCH   4
#define SEQ     2048
#define M_TOT   (BATCH*SEQ)   // 8192

typedef unsigned short ushort_t;
typedef __attribute__((ext_vector_type(8))) short  short8;
typedef __attribute__((ext_vector_type(4))) float  floatx4;

__device__ __forceinline__ float bf2f(ushort_t s) {
    return __uint_as_float(((unsigned int)s) << 16);
}
__device__ __forceinline__ ushort_t f2bf(float f) {
    unsigned int u = __float_as_uint(f);
    u += 0x7fff + ((u >> 16) & 1);   // round-to-nearest-even
    return (ushort_t)(u >> 16);
}

// ---------------------------------------------------------------------------
// dtype detector: sample even-indexed ushorts of x. bf16 data -> biased-exp
// field in [0x3800,0x4380] (|v| in [2^-15, 2^8]) ~always; fp32 low-mantissa
// halves land there ~9%. flag[0]=1 => inputs are bf16; flag[1]=0 always.
// ---------------------------------------------------------------------------
__global__ void detect_dtype(const ushort_t* __restrict__ x, int* __restrict__ flag)
{
    const int t = threadIdx.x;
    int cnt = 0;
    for (int i = t; i < 512; i += 64) {
        ushort_t e = x[2 * i] & 0x7F80;
        cnt += (e >= 0x3800 && e <= 0x4380) ? 1 : 0;
    }
    for (int off = 32; off > 0; off >>= 1) cnt += __shfl_down(cnt, off, 64);
    if (t == 0) { flag[0] = (cnt >= 256) ? 1 : 0; flag[1] = 0; }
}

// small vector (bias / ln params) -> canonical fp32
__global__ void cvt_vec_f32(const void* __restrict__ src, float* __restrict__ dst,
                            int n, const int* __restrict__ flag)
{
    const int i = blockIdx.x * 256 + threadIdx.x;
    if (i >= n) return;
    if (*flag) dst[i] = bf2f(((const ushort_t*)src)[i]);
    else       dst[i] = ((const float*)src)[i];
}

// ---------------------------------------------------------------------------
// weight transpose: in[K][N] (bf16 or fp32 per flag) -> out[N][K] bf16
// grid (N/64, K/64), block 256
// ---------------------------------------------------------------------------
__global__ __launch_bounds__(256) void transpose_to_bf16(
    const void* __restrict__ in, ushort_t* __restrict__ out, int K, int N,
    const int* __restrict__ flag)
{
    __shared__ ushort_t tile[64 * 72];
    const int n0 = blockIdx.x * 64, k0 = blockIdx.y * 64;
    const int t = threadIdx.x, sr = t >> 2, sc = (t & 3) * 16;
    const long g = (long)(k0 + sr) * N + n0 + sc;
    ushort_t cv[16];
    if (*flag) {
        const ushort_t* p = (const ushort_t*)in;
        #pragma unroll
        for (int j = 0; j < 16; j++) cv[j] = p[g + j];
    } else {
        const float* p = (const float*)in;
        #pragma unroll
        for (int j = 0; j < 16; j += 4) {
            float4 fv = *(const float4*)&p[g + j];
            cv[j] = f2bf(fv.x); cv[j+1] = f2bf(fv.y);
            cv[j+2] = f2bf(fv.z); cv[j+3] = f2bf(fv.w);
        }
    }
    #pragma unroll
    for (int j = 0; j < 16; j++) tile[sr * 72 + sc + j] = cv[j];
    __syncthreads();
    __attribute__((aligned(16))) ushort_t tmp[16];
    #pragma unroll
    for (int j = 0; j < 16; j++) tmp[j] = tile[(sc + j) * 72 + sr];
    const long go = (long)(n0 + sr) * K + k0 + sc;
    *(int4*)&out[go]     = *(const int4*)&tmp[0];
    *(int4*)&out[go + 8] = *(const int4*)&tmp[8];
}

// ---------------------------------------------------------------------------
// Tensor1DNorm: mean, unbiased std (ddof=1), eps added to std.
// x raw (bf16 or fp32 per flag), alpha/beta fp32, out bf16.
// ---------------------------------------------------------------------------
__global__ __launch_bounds__(256) void ln_kernel(
    const void* __restrict__ xraw, const float* __restrict__ alpha,
    const float* __restrict__ beta, ushort_t* __restrict__ out,
    const int* __restrict__ flag)
{
    __shared__ float red[8];
    __shared__ float stats[2];
    const int row = blockIdx.x, t = threadIdx.x;
    const long idx = (long)row * D_MODEL + t * 4;
    float v0, v1, v2, v3;
    if (*flag) {
        ushort4 u = *(const ushort4*)&((const ushort_t*)xraw)[idx];
        v0 = bf2f(u.x); v1 = bf2f(u.y); v2 = bf2f(u.z); v3 = bf2f(u.w);
    } else {
        float4 fv = *(const float4*)&((const float*)xraw)[idx];
        v0 = fv.x; v1 = fv.y; v2 = fv.z; v3 = fv.w;
    }
    float s  = v0 + v1 + v2 + v3;
    float s2 = v0 * v0 + v1 * v1 + v2 * v2 + v3 * v3;
    for (int off = 32; off > 0; off >>= 1) {
        s  += __shfl_down(s,  off, 64);
        s2 += __shfl_down(s2, off, 64);
    }
    const int w = t >> 6, lane = t & 63;
    if (lane == 0) { red[w] = s; red[4 + w] = s2; }
    __syncthreads();
    if (t == 0) {
        float S  = red[0] + red[1] + red[2] + red[3];
        float S2 = red[4] + red[5] + red[6] + red[7];
        float mean = S / D_MODEL;
        float var  = fmaxf((S2 - mean * S) / (D_MODEL - 1), 0.f);
        stats[0] = mean;
        stats[1] = 1.f / (sqrtf(var) + 1e-6f);
    }
    __syncthreads();
    const float mean = stats[0], inv = stats[1];
    float vv[4] = {v0, v1, v2, v3};
    ushort4 o;
    ushort_t* op = (ushort_t*)&o;
    #pragma unroll
    for (int j = 0; j < 4; j++)
        op[j] = f2bf(alpha[t * 4 + j] * (vv[j] - mean) * inv + beta[t * 4 + j]);
    *(ushort4*)&out[idx] = o;
}

// ---------------------------------------------------------------------------
// Shared MFMA core: 128x128 tile, BK=32, 256 threads (4 waves 2x2),
// 4x4 16x16x32 bf16 MFMA per wave. A [M][K] bf16, BT [N][K] bf16.
// ---------------------------------------------------------------------------
#define GEMM_PROLOG()                                                         \
    __shared__ ushort_t As[128 * 48];                                         \
    __shared__ ushort_t Bs[128 * 48];                                         \
    const int m0 = blockIdx.x * 128, n0 = blockIdx.y * 128;                   \
    const int t = threadIdx.x;                                                \
    const int w = t >> 6, lane = t & 63, quad = lane >> 4, l15 = lane & 15;   \
    const int wm = (w >> 1) * 64, wn = (w & 1) * 64;                          \
    const int sr = t >> 1, sc = (t & 1) * 16;                                 \
    floatx4 acc[4][4] = {};

#define GEMM_KLOOP(Apt, Bpt, AROW, BROW, KLEN)                                \
    for (int k0 = 0; k0 < (KLEN); k0 += 32) {                                 \
        *(int4*)&As[sr * 48 + sc]     = *(const int4*)&(Apt)[(AROW) + k0 + sc];     \
        *(int4*)&As[sr * 48 + sc + 8] = *(const int4*)&(Apt)[(AROW) + k0 + sc + 8]; \
        *(int4*)&Bs[sr * 48 + sc]     = *(const int4*)&(Bpt)[(BROW) + k0 + sc];     \
        *(int4*)&Bs[sr * 48 + sc + 8] = *(const int4*)&(Bpt)[(BROW) + k0 + sc + 8]; \
        __syncthreads();                                                      \
        short8 af[4], bf[4];                                                  \
        _Pragma("unroll")                                                     \
        for (int i = 0; i < 4; i++)                                           \
            af[i] = *(const short8*)&As[(wm + i * 16 + l15) * 48 + quad * 8]; \
        _Pragma("unroll")                                                     \
        for (int j = 0; j < 4; j++)                                           \
            bf[j] = *(const short8*)&Bs[(wn + j * 16 + l15) * 48 + quad * 8]; \
        _Pragma("unroll")                                                     \
        for (int i = 0; i < 4; i++) {                                         \
            _Pragma("unroll")                                                 \
            for (int j = 0; j < 4; j++)                                       \
                acc[i][j] = __builtin_amdgcn_mfma_f32_16x16x32_bf16(          \
                    af[i], bf[j], acc[i][j], 0, 0, 0);                        \
        }                                                                     \
        __syncthreads();                                                      \
    }

// QKV: C bf16 = A @ BT^T + bias
__global__ __launch_bounds__(256) void gemm_bias_bf16(
    const ushort_t* __restrict__ A, const ushort_t* __restrict__ BT,
    const float* __restrict__ bias, ushort_t* __restrict__ C, int M, int N, int K)
{
    GEMM_PROLOG();
    const long arow = (long)(m0 + sr) * K;
    const long brow = (long)(n0 + sr) * K;
    GEMM_KLOOP(A, BT, arow, brow, K);
    #pragma unroll
    for (int j = 0; j < 4; j++) {
        const int n = n0 + wn + j * 16 + l15;
        const float bv = bias[n];
        #pragma unroll
        for (int i = 0; i < 4; i++) {
            const int mbase = m0 + wm + i * 16 + quad * 4;
            #pragma unroll
            for (int r = 0; r < 4; r++)
                C[(long)(mbase + r) * N + n] = f2bf(acc[i][j][r] + bv);
        }
    }
}

// O-proj: trunk fp32 = A @ BT^T + bias + raw-x residual (flag-typed)
__global__ __launch_bounds__(256) void gemm_bias_res_trunk(
    const ushort_t* __restrict__ A, const ushort_t* __restrict__ BT,
    const float* __restrict__ bias, const void* __restrict__ res,
    float* __restrict__ C, int M, int N, int K, const int* __restrict__ flag)
{
    GEMM_PROLOG();
    const int fl = *flag;
    const long arow = (long)(m0 + sr) * K;
    const long brow = (long)(n0 + sr) * K;
    GEMM_KLOOP(A, BT, arow, brow, K);
    #pragma unroll
    for (int j = 0; j < 4; j++) {
        const int n = n0 + wn + j * 16 + l15;
        const float bv = bias[n];
        #pragma unroll
        for (int i = 0; i < 4; i++) {
            const int mbase = m0 + wm + i * 16 + quad * 4;
            #pragma unroll
            for (int r = 0; r < 4; r++) {
                const long idx = (long)(mbase + r) * N + n;
                const float rv = fl ? bf2f(((const ushort_t*)res)[idx])
                                    : ((const float*)res)[idx];
                C[idx] = acc[i][j][r] + bv + rv;
            }
        }
    }
}

// FF1 quarter: C[M][Nc] bf16 = relu(A @ BT[noff..]^T + bias[noff..])
__global__ __launch_bounds__(256) void gemm_relu_slice(
    const ushort_t* __restrict__ A, const ushort_t* __restrict__ BT,
    const float* __restrict__ bias, ushort_t* __restrict__ C,
    int M, int Nc, int K, int noff)
{
    GEMM_PROLOG();
    const long arow = (long)(m0 + sr) * K;
    const long brow = (long)(noff + n0 + sr) * K;
    GEMM_KLOOP(A, BT, arow, brow, K);
    #pragma unroll
    for (int j = 0; j < 4; j++) {
        const int n = n0 + wn + j * 16 + l15;
        const float bv = bias[noff + n];
        #pragma unroll
        for (int i = 0; i < 4; i++) {
            const int mbase = m0 + wm + i * 16 + quad * 4;
            #pragma unroll
            for (int r = 0; r < 4; r++)
                C[(long)(mbase + r) * Nc + n] = f2bf(fmaxf(acc[i][j][r] + bv, 0.f));
        }
    }
}

// FF2 quarter accumulate into trunk: PASS0: C = C + bias + partial (C holds res)
//                                    PASS1: C += partial
__global__ __launch_bounds__(256) void gemm_acc_slice(
    const ushort_t* __restrict__ A, const ushort_t* __restrict__ BT,
    const float* __restrict__ bias, float* __restrict__ C,
    int M, int N, int Kc, int koff, int Kfull, int pass0)
{
    GEMM_PROLOG();
    const long arow = (long)(m0 + sr) * Kc;
    const long brow = (long)(n0 + sr) * Kfull + koff;
    GEMM_KLOOP(A, BT, arow, brow, Kc);
    #pragma unroll
    for (int j = 0; j < 4; j++) {
        const int n = n0 + wn + j * 16 + l15;
        const float bv = pass0 ? bias[n] : 0.f;
        #pragma unroll
        for (int i = 0; i < 4; i++) {
            const int mbase = m0 + wm + i * 16 + quad * 4;
            #pragma unroll
            for (int r = 0; r < 4; r++) {
                const long idx = (long)(mbase + r) * N + n;
                C[idx] = C[idx] + bv + acc[i][j][r];
            }
        }
    }
}

// finalize: d_out (dtype per flag) = trunk fp32
__global__ __launch_bounds__(256) void finalize_out(
    const float* __restrict__ trunk, void* __restrict__ out,
    const int* __restrict__ flag)
{
    const long i = ((long)blockIdx.x * 256 + threadIdx.x) * 4;
    float4 tv = *(const float4*)&trunk[i];
    if (*flag) {
        ushort4 o = { f2bf(tv.x), f2bf(tv.y), f2bf(tv.z), f2bf(tv.w) };
        *(ushort4*)&((ushort_t*)out)[i] = o;
    } else {
        *(float4*)&((float*)out)[i] = tv;
    }
}

// ---------------------------------------------------------------------------
// Flash attention: grid (S/64, B*H), block 256 (4 waves x 16 Q rows).
// ---------------------------------------------------------------------------
__global__ __launch_bounds__(256) void attn_kernel(
    const ushort_t* __restrict__ q, const ushort_t* __restrict__ k,
    const ushort_t* __restrict__ v, const int* __restrict__ mask,
    ushort_t* __restrict__ out)
{
    __shared__ ushort_t Qs[64 * 72];
    __shared__ ushort_t Ks[64 * 72];
    __shared__ ushort_t Vt[64 * 72];
    __shared__ ushort_t Ps[64 * 72];
    const int qt = blockIdx.x, bh = blockIdx.y;
    const int b = bh >> 4, h = bh & 15;
    const int t = threadIdx.x, w = t >> 6, lane = t & 63;
    const int quad = lane >> 4, l15 = lane & 15;
    const long base = (long)b * SEQ * D_MODEL + h * DK;
    const int sr = t >> 2, sc = (t & 3) * 16;
    const int q0 = qt * 64;
    {
        long g = base + (long)(q0 + sr) * D_MODEL + sc;
        *(int4*)&Qs[sr * 72 + sc]     = *(const int4*)&q[g];
        *(int4*)&Qs[sr * 72 + sc + 8] = *(const int4*)&q[g + 8];
    }
    floatx4 o[4] = {};
    float mrow[4] = {-1e30f, -1e30f, -1e30f, -1e30f};
    float lrow[4] = {0.f, 0.f, 0.f, 0.f};

    for (int kt = 0; kt < SEQ / 64; kt++) {
        long g = base + (long)(kt * 64 + sr) * D_MODEL + sc;
        *(int4*)&Ks[sr * 72 + sc]     = *(const int4*)&k[g];
        *(int4*)&Ks[sr * 72 + sc + 8] = *(const int4*)&k[g + 8];
        __attribute__((aligned(16))) ushort_t tmp[16];
        *(int4*)&tmp[0] = *(const int4*)&v[g];
        *(int4*)&tmp[8] = *(const int4*)&v[g + 8];
        #pragma unroll
        for (int j = 0; j < 16; j++) Vt[(sc + j) * 72 + sr] = tmp[j];
        __syncthreads();

        floatx4 s[4] = {};
        #pragma unroll
        for (int ks = 0; ks < 2; ks++) {
            short8 aq = *(const short8*)&Qs[(w * 16 + l15) * 72 + ks * 32 + quad * 8];
            #pragma unroll
            for (int nt = 0; nt < 4; nt++) {
                short8 bk = *(const short8*)&Ks[(nt * 16 + l15) * 72 + ks * 32 + quad * 8];
                s[nt] = __builtin_amdgcn_mfma_f32_16x16x32_bf16(aq, bk, s[nt], 0, 0, 0);
            }
        }
        #pragma unroll
        for (int nt = 0; nt < 4; nt++) {
            const int key = kt * 64 + nt * 16 + l15;
            const bool msk = (mask[b * SEQ + key] == 0);
            #pragma unroll
            for (int r = 0; r < 4; r++) {
                float sv = s[nt][r] * 0.125f;
                s[nt][r] = msk ? -1e9f : sv;
            }
        }
        float alpha_r[4];
        #pragma unroll
        for (int r = 0; r < 4; r++) {
            float rm = fmaxf(fmaxf(s[0][r], s[1][r]), fmaxf(s[2][r], s[3][r]));
            for (int off = 1; off < 16; off <<= 1) rm = fmaxf(rm, __shfl_xor(rm, off, 64));
            const float mn = fmaxf(mrow[r], rm);
            const float al = __expf(mrow[r] - mn);
            float sum = 0.f;
            #pragma unroll
            for (int nt = 0; nt < 4; nt++) {
                float p = __expf(s[nt][r] - mn);
                s[nt][r] = p;
                sum += p;
            }
            for (int off = 1; off < 16; off <<= 1) sum += __shfl_xor(sum, off, 64);
            lrow[r] = lrow[r] * al + sum;
            mrow[r] = mn;
            alpha_r[r] = al;
        }
        #pragma unroll
        for (int j = 0; j < 4; j++) {
            #pragma unroll
            for (int r = 0; r < 4; r++) o[j][r] *= alpha_r[r];
        }
        #pragma unroll
        for (int nt = 0; nt < 4; nt++) {
            #pragma unroll
            for (int r = 0; r < 4; r++)
                Ps[(w * 16 + quad * 4 + r) * 72 + nt * 16 + l15] = f2bf(s[nt][r]);
        }
        #pragma unroll
        for (int ks = 0; ks < 2; ks++) {
            short8 ap = *(const short8*)&Ps[(w * 16 + l15) * 72 + ks * 32 + quad * 8];
            #pragma unroll
            for (int j = 0; j < 4; j++) {
                short8 bv = *(const short8*)&Vt[(j * 16 + l15) * 72 + ks * 32 + quad * 8];
                o[j] = __builtin_amdgcn_mfma_f32_16x16x32_bf16(ap, bv, o[j], 0, 0, 0);
            }
        }
        __syncthreads();
    }
    #pragma unroll
    for (int j = 0; j < 4; j++) {
        const int d = j * 16 + l15;
        #pragma unroll
        for (int r = 0; r < 4; r++) {
            const int row = w * 16 + quad * 4 + r;
            out[base + (long)(q0 + row) * D_MODEL + d] = f2bf(o[j][r] / lrow[r]);
        }
    }
}

// ---------------------------------------------------------------------------
// Launch. ws layout (peak 89 MB):
//   0..8   MB : wqT wkT wvT woT (bf16, 2 MB each)
//   8..16  MB : w1T (bf16)     16..24 MB : w2T (bf16)
//   24..25 MB : fp32 params (16 KB slots) + flags
//   25..41 MB : lnbuf bf16  -> attnb -> halfbuf (FF quarters)
//   41..57 MB : qb  ─┐
//   57..73 MB : kb  ─┴─> trunk fp32 (32 MB) after attention
//   73..89 MB : vb  ───> ln2buf after attention
// ---------------------------------------------------------------------------
extern "C" void kernel_launch(void* const* d_in, const int* in_sizes, int n_in,
                              void* d_out, int out_size, void* d_ws, size_t ws_size,
                              hipStream_t stream)
{
    const void* x      = d_in[0];
    const int*  mask   = (const int*)d_in[1];
    const void* wq     = d_in[2];
    const void* bq     = d_in[3];
    const void* wk     = d_in[4];
    const void* bk     = d_in[5];
    const void* wv     = d_in[6];
    const void* bv     = d_in[7];
    const void* wo     = d_in[8];
    const void* bo     = d_in[9];
    const void* w1     = d_in[10];
    const void* b1     = d_in[11];
    const void* w2     = d_in[12];
    const void* b2     = d_in[13];
    const void* alpha1 = d_in[14];
    const void* bias1  = d_in[15];
    const void* alpha2 = d_in[16];
    const void* bias2  = d_in[17];

    char* ws = (char*)d_ws;
    const size_t MB = 1024 * 1024;
    const size_t KB = 1024;
    ushort_t* wqT  = (ushort_t*)(ws + 0 * MB);
    ushort_t* wkT  = (ushort_t*)(ws + 2 * MB);
    ushort_t* wvT  = (ushort_t*)(ws + 4 * MB);
    ushort_t* woT  = (ushort_t*)(ws + 6 * MB);
    ushort_t* w1T  = (ushort_t*)(ws + 8 * MB);
    ushort_t* w2T  = (ushort_t*)(ws + 16 * MB);
    float* bqf  = (float*)(ws + 24 * MB + 0 * 16 * KB);
    float* bkf  = (float*)(ws + 24 * MB + 1 * 16 * KB);
    float* bvf  = (float*)(ws + 24 * MB + 2 * 16 * KB);
    float* bof  = (float*)(ws + 24 * MB + 3 * 16 * KB);
    float* b1f  = (float*)(ws + 24 * MB + 4 * 16 * KB);
    float* b2f  = (float*)(ws + 24 * MB + 5 * 16 * KB);
    float* a1f  = (float*)(ws + 24 * MB + 6 * 16 * KB);
    float* be1f = (float*)(ws + 24 * MB + 7 * 16 * KB);
    float* a2f  = (float*)(ws + 24 * MB + 8 * 16 * KB);
    float* be2f = (float*)(ws + 24 * MB + 9 * 16 * KB);
    int*   flag = (int*)(ws + 24 * MB + 10 * 16 * KB);  // flag[0]=dtype, flag[1]=0
    int*   flagz = flag + 1;
    ushort_t* lnbuf = (ushort_t*)(ws + 25 * MB);
    ushort_t* qb    = (ushort_t*)(ws + 41 * MB);
    ushort_t* kb    = (ushort_t*)(ws + 57 * MB);
    ushort_t* vb    = (ushort_t*)(ws + 73 * MB);
    ushort_t* attnb   = lnbuf;            // after LN1 consumed
    float*    trunk   = (float*)qb;       // 32 MB over qb+kb, after attention
    ushort_t* ln2buf  = vb;               // after attention
    ushort_t* halfbuf = lnbuf;            // FF quarter buffer (16 MB), after O-proj

    dim3 blk(256);
    detect_dtype<<<1, 64, 0, stream>>>((const ushort_t*)x, flag);

    cvt_vec_f32<<<4, blk, 0, stream>>>(bq, bqf, D_MODEL, flag);
    cvt_vec_f32<<<4, blk, 0, stream>>>(bk, bkf, D_MODEL, flag);
    cvt_vec_f32<<<4, blk, 0, stream>>>(bv, bvf, D_MODEL, flag);
    cvt_vec_f32<<<4, blk, 0, stream>>>(bo, bof, D_MODEL, flag);
    cvt_vec_f32<<<16, blk, 0, stream>>>(b1, b1f, D_FF, flag);
    cvt_vec_f32<<<4, blk, 0, stream>>>(b2, b2f, D_MODEL, flag);
    cvt_vec_f32<<<4, blk, 0, stream>>>(alpha1, a1f, D_MODEL, flag);
    cvt_vec_f32<<<4, blk, 0, stream>>>(bias1, be1f, D_MODEL, flag);
    cvt_vec_f32<<<4, blk, 0, stream>>>(alpha2, a2f, D_MODEL, flag);
    cvt_vec_f32<<<4, blk, 0, stream>>>(bias2, be2f, D_MODEL, flag);

    transpose_to_bf16<<<dim3(16, 16), blk, 0, stream>>>(wq, wqT, D_MODEL, D_MODEL, flag);
    transpose_to_bf16<<<dim3(16, 16), blk, 0, stream>>>(wk, wkT, D_MODEL, D_MODEL, flag);
    transpose_to_bf16<<<dim3(16, 16), blk, 0, stream>>>(wv, wvT, D_MODEL, D_MODEL, flag);
    transpose_to_bf16<<<dim3(16, 16), blk, 0, stream>>>(wo, woT, D_MODEL, D_MODEL, flag);
    transpose_to_bf16<<<dim3(64, 16), blk, 0, stream>>>(w1, w1T, D_MODEL, D_FF, flag);
    transpose_to_bf16<<<dim3(16, 64), blk, 0, stream>>>(w2, w2T, D_FF, D_MODEL, flag);

    ln_kernel<<<M_TOT, blk, 0, stream>>>(x, a1f, be1f, lnbuf, flag);

    gemm_bias_bf16<<<dim3(64, 8), blk, 0, stream>>>(lnbuf, wqT, bqf, qb,
                                                    M_TOT, D_MODEL, D_MODEL);
    gemm_bias_bf16<<<dim3(64, 8), blk, 0, stream>>>(lnbuf, wkT, bkf, kb,
                                                    M_TOT, D_MODEL, D_MODEL);
    gemm_bias_bf16<<<dim3(64, 8), blk, 0, stream>>>(lnbuf, wvT, bvf, vb,
                                                    M_TOT, D_MODEL, D_MODEL);

    attn_kernel<<<dim3(SEQ / 64, BATCH * N_HEADS), blk, 0, stream>>>(qb, kb, vb, mask, attnb);

    // trunk = attnb @ woT + bo + x   (overwrites qb+kb, reads attnb in lnbuf)
    gemm_bias_res_trunk<<<dim3(64, 8), blk, 0, stream>>>(attnb, woT, bof, x, trunk,
                                                         M_TOT, D_MODEL, D_MODEL, flag);

    ln_kernel<<<M_TOT, blk, 0, stream>>>(trunk, a2f, be2f, ln2buf, flagz);

    // FF in four D_FF quarters; halfbuf reuses lnbuf (attnb dead after O-proj)
    for (int qtr = 0; qtr < 4; qtr++) {
        const int off = qtr * 1024;
        gemm_relu_slice<<<dim3(64, 8), blk, 0, stream>>>(ln2buf, w1T, b1f, halfbuf,
                                                         M_TOT, 1024, D_MODEL, off);
        gemm_acc_slice<<<dim3(64, 8), blk, 0, stream>>>(halfbuf, w2T, b2f, trunk,
                                                        M_TOT, D_MODEL, 1024, off,
                                                        D_FF, qtr == 0 ? 1 : 0);
    }

    finalize_out<<<M_TOT * D_MODEL / 1024, blk, 0, stream>>>(trunk, d_out, flag);
}

// Round 6
// 781.651 us; speedup vs baseline: 1.1837x; 1.1837x over previous
//
#include <hip/hip_runtime.h>

#define D_MODEL 1024
#define D_FF    4096
#define N_HEADS 16
#define DK      64
#define BATCH   4
#define SEQ     2048
#define M_TOT   (BATCH*SEQ)   // 8192

typedef unsigned short ushort_t;
typedef __attribute__((ext_vector_type(8))) short  short8;
typedef __attribute__((ext_vector_type(4))) float  floatx4;

__device__ __forceinline__ float bf2f(ushort_t s) {
    return __uint_as_float(((unsigned int)s) << 16);
}
__device__ __forceinline__ ushort_t f2bf(float f) {
    unsigned int u = __float_as_uint(f);
    u += 0x7fff + ((u >> 16) & 1);   // round-to-nearest-even
    return (ushort_t)(u >> 16);
}
// async global->LDS, 16B per lane; LDS dest = wave-uniform base + lane*16
__device__ __forceinline__ void gll16(const void* g, void* l) {
    __builtin_amdgcn_global_load_lds(
        (const __attribute__((address_space(1))) void*)g,
        (__attribute__((address_space(3))) void*)l,
        16, 0, 0);
}

// ---------------------------------------------------------------------------
// dtype detector (unchanged from R5 — validated)
// ---------------------------------------------------------------------------
__global__ void detect_dtype(const ushort_t* __restrict__ x, int* __restrict__ flag)
{
    const int t = threadIdx.x;
    int cnt = 0;
    for (int i = t; i < 512; i += 64) {
        ushort_t e = x[2 * i] & 0x7F80;
        cnt += (e >= 0x3800 && e <= 0x4380) ? 1 : 0;
    }
    for (int off = 32; off > 0; off >>= 1) cnt += __shfl_down(cnt, off, 64);
    if (t == 0) { flag[0] = (cnt >= 256) ? 1 : 0; flag[1] = 0; }
}

__global__ void cvt_vec_f32(const void* __restrict__ src, float* __restrict__ dst,
                            int n, float scale, const int* __restrict__ flag)
{
    const int i = blockIdx.x * 256 + threadIdx.x;
    if (i >= n) return;
    if (*flag) dst[i] = bf2f(((const ushort_t*)src)[i]) * scale;
    else       dst[i] = ((const float*)src)[i] * scale;
}

// ---------------------------------------------------------------------------
// weight transpose (+optional scale): in[K][N] -> out[N][K] bf16
// ---------------------------------------------------------------------------
__global__ __launch_bounds__(256) void transpose_to_bf16(
    const void* __restrict__ in, ushort_t* __restrict__ out, int K, int N,
    float scale, const int* __restrict__ flag)
{
    __shared__ ushort_t tile[64 * 72];
    const int n0 = blockIdx.x * 64, k0 = blockIdx.y * 64;
    const int t = threadIdx.x, sr = t >> 2, sc = (t & 3) * 16;
    const long g = (long)(k0 + sr) * N + n0 + sc;
    ushort_t cv[16];
    if (*flag) {
        const ushort_t* p = (const ushort_t*)in;
        #pragma unroll
        for (int j = 0; j < 16; j++) cv[j] = f2bf(bf2f(p[g + j]) * scale);
    } else {
        const float* p = (const float*)in;
        #pragma unroll
        for (int j = 0; j < 16; j += 4) {
            float4 fv = *(const float4*)&p[g + j];
            cv[j] = f2bf(fv.x * scale); cv[j+1] = f2bf(fv.y * scale);
            cv[j+2] = f2bf(fv.z * scale); cv[j+3] = f2bf(fv.w * scale);
        }
    }
    #pragma unroll
    for (int j = 0; j < 16; j++) tile[sr * 72 + sc + j] = cv[j];
    __syncthreads();
    __attribute__((aligned(16))) ushort_t tmp[16];
    #pragma unroll
    for (int j = 0; j < 16; j++) tmp[j] = tile[(sc + j) * 72 + sr];
    const long go = (long)(n0 + sr) * K + k0 + sc;
    *(int4*)&out[go]     = *(const int4*)&tmp[0];
    *(int4*)&out[go + 8] = *(const int4*)&tmp[8];
}

// ---------------------------------------------------------------------------
// Tensor1DNorm (unchanged from R5 — validated)
// ---------------------------------------------------------------------------
__global__ __launch_bounds__(256) void ln_kernel(
    const void* __restrict__ xraw, const float* __restrict__ alpha,
    const float* __restrict__ beta, ushort_t* __restrict__ out,
    const int* __restrict__ flag)
{
    __shared__ float red[8];
    __shared__ float stats[2];
    const int row = blockIdx.x, t = threadIdx.x;
    const long idx = (long)row * D_MODEL + t * 4;
    float v0, v1, v2, v3;
    if (*flag) {
        ushort4 u = *(const ushort4*)&((const ushort_t*)xraw)[idx];
        v0 = bf2f(u.x); v1 = bf2f(u.y); v2 = bf2f(u.z); v3 = bf2f(u.w);
    } else {
        float4 fv = *(const float4*)&((const float*)xraw)[idx];
        v0 = fv.x; v1 = fv.y; v2 = fv.z; v3 = fv.w;
    }
    float s  = v0 + v1 + v2 + v3;
    float s2 = v0 * v0 + v1 * v1 + v2 * v2 + v3 * v3;
    for (int off = 32; off > 0; off >>= 1) {
        s  += __shfl_down(s,  off, 64);
        s2 += __shfl_down(s2, off, 64);
    }
    const int w = t >> 6, lane = t & 63;
    if (lane == 0) { red[w] = s; red[4 + w] = s2; }
    __syncthreads();
    if (t == 0) {
        float S  = red[0] + red[1] + red[2] + red[3];
        float S2 = red[4] + red[5] + red[6] + red[7];
        float mean = S / D_MODEL;
        float var  = fmaxf((S2 - mean * S) / (D_MODEL - 1), 0.f);
        stats[0] = mean;
        stats[1] = 1.f / (sqrtf(var) + 1e-6f);
    }
    __syncthreads();
    const float mean = stats[0], inv = stats[1];
    float vv[4] = {v0, v1, v2, v3};
    ushort4 o;
    ushort_t* op = (ushort_t*)&o;
    #pragma unroll
    for (int j = 0; j < 4; j++)
        op[j] = f2bf(alpha[t * 4 + j] * (vv[j] - mean) * inv + beta[t * 4 + j]);
    *(ushort4*)&out[idx] = o;
}

// ---------------------------------------------------------------------------
// m97-style GEMM core: 128x128 tile, BK=32, global_load_lds(16B) staging.
// LDS layout [128][32] unpadded, lane i of wave w stages at base + 16*i.
// ---------------------------------------------------------------------------
#define GEMM_PROLOG()                                                         \
    __shared__ ushort_t As[128 * 32];                                         \
    __shared__ ushort_t Bs[128 * 32];                                         \
    const int m0 = blockIdx.x * 128, n0 = blockIdx.y * 128;                   \
    const int t = threadIdx.x;                                                \
    const int w = t >> 6, lane = t & 63, quad = lane >> 4, l15 = lane & 15;   \
    const int wm = (w >> 1) * 64, wn = (w & 1) * 64;                          \
    floatx4 acc[4][4] = {};

#define GEMM_KLOOP(Abase, LDA, Bbase, LDB, KLEN)                              \
    {                                                                         \
    const ushort_t* gA = (Abase) + (long)(m0 + w * 32 + (lane >> 2)) * (LDA)  \
                         + (lane & 3) * 8;                                    \
    const ushort_t* gB = (Bbase) + (long)(n0 + w * 32 + (lane >> 2)) * (LDB)  \
                         + (lane & 3) * 8;                                    \
    for (int k0 = 0; k0 < (KLEN); k0 += 32) {                                 \
        gll16(gA + k0,                     &As[(w * 32) * 32]);               \
        gll16(gA + k0 + 16 * (long)(LDA), &As[(w * 32 + 16) * 32]);           \
        gll16(gB + k0,                     &Bs[(w * 32) * 32]);               \
        gll16(gB + k0 + 16 * (long)(LDB), &Bs[(w * 32 + 16) * 32]);           \
        __syncthreads();                                                      \
        short8 af[4], bf[4];                                                  \
        _Pragma("unroll")                                                     \
        for (int i = 0; i < 4; i++)                                           \
            af[i] = *(const short8*)&As[(wm + i * 16 + l15) * 32 + quad * 8]; \
        _Pragma("unroll")                                                     \
        for (int j = 0; j < 4; j++)                                           \
            bf[j] = *(const short8*)&Bs[(wn + j * 16 + l15) * 32 + quad * 8]; \
        _Pragma("unroll")                                                     \
        for (int i = 0; i < 4; i++) {                                         \
            _Pragma("unroll")                                                 \
            for (int j = 0; j < 4; j++)                                       \
                acc[i][j] = __builtin_amdgcn_mfma_f32_16x16x32_bf16(          \
                    af[i], bf[j], acc[i][j], 0, 0, 0);                        \
        }                                                                     \
        __syncthreads();                                                      \
    }                                                                         \
    }

// Q/K projections: C bf16 = A @ BT^T + bias
__global__ __launch_bounds__(256) void gemm_bias_bf16(
    const ushort_t* __restrict__ A, const ushort_t* __restrict__ BT,
    const float* __restrict__ bias, ushort_t* __restrict__ C, int M, int N, int K)
{
    GEMM_PROLOG();
    GEMM_KLOOP(A, K, BT, K, K);
    #pragma unroll
    for (int j = 0; j < 4; j++) {
        const int n = n0 + wn + j * 16 + l15;
        const float bv = bias[n];
        #pragma unroll
        for (int i = 0; i < 4; i++) {
            const int mbase = m0 + wm + i * 16 + quad * 4;
            #pragma unroll
            for (int r = 0; r < 4; r++)
                C[(long)(mbase + r) * N + n] = f2bf(acc[i][j][r] + bv);
        }
    }
}

// V projection: writes V^T layout [B][H][DK][S] bf16 (packed ushort4 stores)
__global__ __launch_bounds__(256) void gemm_bias_vt(
    const ushort_t* __restrict__ A, const ushort_t* __restrict__ BT,
    const float* __restrict__ bias, ushort_t* __restrict__ VT, int M, int N, int K)
{
    GEMM_PROLOG();
    GEMM_KLOOP(A, K, BT, K, K);
    #pragma unroll
    for (int j = 0; j < 4; j++) {
        const int n = n0 + wn + j * 16 + l15;   // n = h*64 + d
        const float bv = bias[n];
        #pragma unroll
        for (int i = 0; i < 4; i++) {
            const int mb_ = m0 + wm + i * 16 + quad * 4;   // m = b*2048 + s
            ushort4 pv;
            #pragma unroll
            for (int r = 0; r < 4; r++)
                ((ushort_t*)&pv)[r] = f2bf(acc[i][j][r] + bv);
            const long idx = ((long)(mb_ >> 11) * 1024 + n) * 2048 + (mb_ & 2047);
            *(ushort4*)&VT[idx] = pv;
        }
    }
}

// O-proj: trunk fp32 = A @ BT^T + bias + raw-x residual (flag-typed)
__global__ __launch_bounds__(256) void gemm_bias_res_trunk(
    const ushort_t* __restrict__ A, const ushort_t* __restrict__ BT,
    const float* __restrict__ bias, const void* __restrict__ res,
    float* __restrict__ C, int M, int N, int K, const int* __restrict__ flag)
{
    GEMM_PROLOG();
    const int fl = *flag;
    GEMM_KLOOP(A, K, BT, K, K);
    #pragma unroll
    for (int j = 0; j < 4; j++) {
        const int n = n0 + wn + j * 16 + l15;
        const float bv = bias[n];
        #pragma unroll
        for (int i = 0; i < 4; i++) {
            const int mbase = m0 + wm + i * 16 + quad * 4;
            #pragma unroll
            for (int r = 0; r < 4; r++) {
                const long idx = (long)(mbase + r) * N + n;
                const float rv = fl ? bf2f(((const ushort_t*)res)[idx])
                                    : ((const float*)res)[idx];
                C[idx] = acc[i][j][r] + bv + rv;
            }
        }
    }
}

// FF1 quarter: C[M][Nc] bf16 = relu(A @ BT[noff..]^T + bias[noff..])
__global__ __launch_bounds__(256) void gemm_relu_slice(
    const ushort_t* __restrict__ A, const ushort_t* __restrict__ BT,
    const float* __restrict__ bias, ushort_t* __restrict__ C,
    int M, int Nc, int K, int noff)
{
    GEMM_PROLOG();
    const ushort_t* BTo = BT + (long)noff * K;
    GEMM_KLOOP(A, K, BTo, K, K);
    #pragma unroll
    for (int j = 0; j < 4; j++) {
        const int n = n0 + wn + j * 16 + l15;
        const float bv = bias[noff + n];
        #pragma unroll
        for (int i = 0; i < 4; i++) {
            const int mbase = m0 + wm + i * 16 + quad * 4;
            #pragma unroll
            for (int r = 0; r < 4; r++)
                C[(long)(mbase + r) * Nc + n] = f2bf(fmaxf(acc[i][j][r] + bv, 0.f));
        }
    }
}

// FF2 quarter accumulate into trunk (pass0: += bias too; trunk holds residual)
__global__ __launch_bounds__(256) void gemm_acc_slice(
    const ushort_t* __restrict__ A, const ushort_t* __restrict__ BT,
    const float* __restrict__ bias, float* __restrict__ C,
    int M, int N, int Kc, int koff, int Kfull, int pass0)
{
    GEMM_PROLOG();
    const ushort_t* BTo = BT + koff;
    GEMM_KLOOP(A, Kc, BTo, Kfull, Kc);
    #pragma unroll
    for (int j = 0; j < 4; j++) {
        const int n = n0 + wn + j * 16 + l15;
        const float bv = pass0 ? bias[n] : 0.f;
        #pragma unroll
        for (int i = 0; i < 4; i++) {
            const int mbase = m0 + wm + i * 16 + quad * 4;
            #pragma unroll
            for (int r = 0; r < 4; r++) {
                const long idx = (long)(mbase + r) * N + n;
                C[idx] = C[idx] + bv + acc[i][j][r];
            }
        }
    }
}

__global__ __launch_bounds__(256) void finalize_out(
    const float* __restrict__ trunk, void* __restrict__ out,
    const int* __restrict__ flag)
{
    const long i = ((long)blockIdx.x * 256 + threadIdx.x) * 4;
    float4 tv = *(const float4*)&trunk[i];
    if (*flag) {
        ushort4 o = { f2bf(tv.x), f2bf(tv.y), f2bf(tv.z), f2bf(tv.w) };
        *(ushort4*)&((ushort_t*)out)[i] = o;
    } else {
        *(float4*)&((float*)out)[i] = tv;
    }
}

// ---------------------------------------------------------------------------
// Flash attention v2: S^T formulation. grid (S/64, B*H), block 256 (4 waves).
// q [B,S,1024] bf16 PRE-SCALED by 1/8; k [B,S,1024] bf16; vt [B,H,DK,S] bf16.
// S^T = K·Q^T (A=K, B=Q): per-thread regs hold S^T[key=nt*16+quad*4+r][q=l15].
// Softmax per q: in-thread over 16 regs + 2 shfl_xor across quads.
// PV: A = P[q][key] via LDS (ds_write_b64, 2-way banks), B = V^T direct.
// ---------------------------------------------------------------------------
__global__ __launch_bounds__(256) void attn_kernel(
    const ushort_t* __restrict__ q, const ushort_t* __restrict__ k,
    const ushort_t* __restrict__ vt, const int* __restrict__ mask,
    ushort_t* __restrict__ out)
{
    __shared__ ushort_t Qs[64 * 72];
    __shared__ ushort_t Ks[64 * 72];
    __shared__ ushort_t Vs[64 * 72];
    __shared__ ushort_t Ps[64 * 72];
    __shared__ float Mb[64];
    __shared__ float Asm[64];
    __shared__ float Lsm[64];
    const int qt = blockIdx.x, bh = blockIdx.y;
    const int b = bh >> 4, h = bh & 15;
    const int t = threadIdx.x, w = t >> 6, lane = t & 63;
    const int quad = lane >> 4, l15 = lane & 15;
    const int sr = t >> 2, sc = (t & 3) * 16;
    const int q0 = qt * 64;
    const long rowbase = (long)b * SEQ * D_MODEL + (long)h * DK;
    const long vtbase  = ((long)(b * 16 + h) * DK) * SEQ;
    {   // stage Q once: rows q0+sr, 64 cols of head h (each wave stages own rows)
        const long g = rowbase + (long)(q0 + sr) * D_MODEL + sc;
        *(int4*)&Qs[sr * 72 + sc]     = *(const int4*)&q[g];
        *(int4*)&Qs[sr * 72 + sc + 8] = *(const int4*)&q[g + 8];
    }
    floatx4 o[4] = {};
    float mrow = -1e30f, lrow = 0.f;

    for (int kt = 0; kt < SEQ / 64; kt++) {
        {   // stage K rows (keys) and V^T rows (d, keys contiguous)
            const long gk = rowbase + (long)(kt * 64 + sr) * D_MODEL + sc;
            *(int4*)&Ks[sr * 72 + sc]     = *(const int4*)&k[gk];
            *(int4*)&Ks[sr * 72 + sc + 8] = *(const int4*)&k[gk + 8];
            const long gv = vtbase + (long)sr * SEQ + kt * 64 + sc;
            *(int4*)&Vs[sr * 72 + sc]     = *(const int4*)&vt[gv];
            *(int4*)&Vs[sr * 72 + sc + 8] = *(const int4*)&vt[gv + 8];
        }
        if (t < 64)
            Mb[t] = (mask[b * SEQ + kt * 64 + t] == 0) ? -1e9f : 0.0f;
        __syncthreads();

        // S^T = K·Q^T  (A=K rows=key, B=Q rows=q); q already scaled by 1/8
        floatx4 s[4] = {};
        #pragma unroll
        for (int ks = 0; ks < 2; ks++) {
            short8 bq = *(const short8*)&Qs[(w * 16 + l15) * 72 + ks * 32 + quad * 8];
            #pragma unroll
            for (int nt = 0; nt < 4; nt++) {
                short8 ak = *(const short8*)&Ks[(nt * 16 + l15) * 72 + ks * 32 + quad * 8];
                s[nt] = __builtin_amdgcn_mfma_f32_16x16x32_bf16(ak, bq, s[nt], 0, 0, 0);
            }
        }
        // mask bias + per-q max (16 in-thread + 2 shfls across quads)
        float tmax = -1e30f;
        #pragma unroll
        for (int nt = 0; nt < 4; nt++) {
            float4 mb4 = *(const float4*)&Mb[nt * 16 + quad * 4];
            const float* mbp = (const float*)&mb4;
            #pragma unroll
            for (int r = 0; r < 4; r++) {
                s[nt][r] += mbp[r];
                tmax = fmaxf(tmax, s[nt][r]);
            }
        }
        tmax = fmaxf(tmax, __shfl_xor(tmax, 16, 64));
        tmax = fmaxf(tmax, __shfl_xor(tmax, 32, 64));
        const float mn = fmaxf(mrow, tmax);
        const float al = __expf(mrow - mn);
        float sum = 0.f;
        #pragma unroll
        for (int nt = 0; nt < 4; nt++) {
            ushort4 pv;
            #pragma unroll
            for (int r = 0; r < 4; r++) {
                float p = __expf(s[nt][r] - mn);
                sum += p;
                ((ushort_t*)&pv)[r] = f2bf(p);
            }
            // P[q=l15][key=nt*16+quad*4..+3] — 8B write, 2-way banks
            *(ushort4*)&Ps[(w * 16 + l15) * 72 + nt * 16 + quad * 4] = pv;
        }
        sum += __shfl_xor(sum, 16, 64);
        sum += __shfl_xor(sum, 32, 64);
        lrow = lrow * al + sum;
        mrow = mn;
        // broadcast alpha from q=l15 lanes to q=quad*4+r accumulator layout
        Asm[w * 16 + l15] = al;
        float4 al4 = *(const float4*)&Asm[w * 16 + quad * 4];
        const float* alp = (const float*)&al4;
        #pragma unroll
        for (int j = 0; j < 4; j++) {
            #pragma unroll
            for (int r = 0; r < 4; r++) o[j][r] *= alp[r];
        }
        // O += P·V  (A = P[q][key] from Ps, B = V^T[d][key] from Vs)
        #pragma unroll
        for (int ks = 0; ks < 2; ks++) {
            short8 ap = *(const short8*)&Ps[(w * 16 + l15) * 72 + ks * 32 + quad * 8];
            #pragma unroll
            for (int j = 0; j < 4; j++) {
                short8 bv = *(const short8*)&Vs[(j * 16 + l15) * 72 + ks * 32 + quad * 8];
                o[j] = __builtin_amdgcn_mfma_f32_16x16x32_bf16(ap, bv, o[j], 0, 0, 0);
            }
        }
        __syncthreads();
    }
    // epilogue: O C-layout row q=quad*4+r, col d=j*16+l15; l broadcast via LDS
    Lsm[w * 16 + l15] = lrow;
    float4 lr4 = *(const float4*)&Lsm[w * 16 + quad * 4];
    float inv[4];
    #pragma unroll
    for (int r = 0; r < 4; r++) inv[r] = 1.f / ((const float*)&lr4)[r];
    #pragma unroll
    for (int j = 0; j < 4; j++) {
        const int d = j * 16 + l15;
        #pragma unroll
        for (int r = 0; r < 4; r++) {
            const int row = q0 + w * 16 + quad * 4 + r;
            out[rowbase + (long)row * D_MODEL + d] = f2bf(o[j][r] * inv[r]);
        }
    }
}

// ---------------------------------------------------------------------------
// Launch. ws layout (peak 89 MB), same as validated R5:
//   0..8   MB : wqT wkT wvT woT     8..16 MB : w1T     16..24 MB : w2T
//   24..25 MB : fp32 params + flags
//   25..41 MB : lnbuf -> attnb -> halfbuf
//   41..57 MB : qb ─┐  57..73 MB : kb ─┴─> trunk fp32 (32 MB)
//   73..89 MB : vtb (V^T [B,H,DK,S]) ───> ln2buf after attention
// ---------------------------------------------------------------------------
extern "C" void kernel_launch(void* const* d_in, const int* in_sizes, int n_in,
                              void* d_out, int out_size, void* d_ws, size_t ws_size,
                              hipStream_t stream)
{
    const void* x      = d_in[0];
    const int*  mask   = (const int*)d_in[1];
    const void* wq     = d_in[2];
    const void* bq     = d_in[3];
    const void* wk     = d_in[4];
    const void* bk     = d_in[5];
    const void* wv     = d_in[6];
    const void* bv     = d_in[7];
    const void* wo     = d_in[8];
    const void* bo     = d_in[9];
    const void* w1     = d_in[10];
    const void* b1     = d_in[11];
    const void* w2     = d_in[12];
    const void* b2     = d_in[13];
    const void* alpha1 = d_in[14];
    const void* bias1  = d_in[15];
    const void* alpha2 = d_in[16];
    const void* bias2  = d_in[17];

    char* ws = (char*)d_ws;
    const size_t MB = 1024 * 1024;
    const size_t KB = 1024;
    ushort_t* wqT  = (ushort_t*)(ws + 0 * MB);
    ushort_t* wkT  = (ushort_t*)(ws + 2 * MB);
    ushort_t* wvT  = (ushort_t*)(ws + 4 * MB);
    ushort_t* woT  = (ushort_t*)(ws + 6 * MB);
    ushort_t* w1T  = (ushort_t*)(ws + 8 * MB);
    ushort_t* w2T  = (ushort_t*)(ws + 16 * MB);
    float* bqf  = (float*)(ws + 24 * MB + 0 * 16 * KB);
    float* bkf  = (float*)(ws + 24 * MB + 1 * 16 * KB);
    float* bvf  = (float*)(ws + 24 * MB + 2 * 16 * KB);
    float* bof  = (float*)(ws + 24 * MB + 3 * 16 * KB);
    float* b1f  = (float*)(ws + 24 * MB + 4 * 16 * KB);
    float* b2f  = (float*)(ws + 24 * MB + 5 * 16 * KB);
    float* a1f  = (float*)(ws + 24 * MB + 6 * 16 * KB);
    float* be1f = (float*)(ws + 24 * MB + 7 * 16 * KB);
    float* a2f  = (float*)(ws + 24 * MB + 8 * 16 * KB);
    float* be2f = (float*)(ws + 24 * MB + 9 * 16 * KB);
    int*   flag  = (int*)(ws + 24 * MB + 10 * 16 * KB);
    int*   flagz = flag + 1;
    ushort_t* lnbuf = (ushort_t*)(ws + 25 * MB);
    ushort_t* qb    = (ushort_t*)(ws + 41 * MB);
    ushort_t* kb    = (ushort_t*)(ws + 57 * MB);
    ushort_t* vtb   = (ushort_t*)(ws + 73 * MB);
    ushort_t* attnb   = lnbuf;
    float*    trunk   = (float*)qb;       // 32 MB over qb+kb after attention
    ushort_t* ln2buf  = vtb;              // vtb dead after attention
    ushort_t* halfbuf = lnbuf;            // FF quarter buffer

    dim3 blk(256);
    detect_dtype<<<1, 64, 0, stream>>>((const ushort_t*)x, flag);

    cvt_vec_f32<<<4, blk, 0, stream>>>(bq, bqf, D_MODEL, 0.125f, flag);  // 1/8 folded
    cvt_vec_f32<<<4, blk, 0, stream>>>(bk, bkf, D_MODEL, 1.f, flag);
    cvt_vec_f32<<<4, blk, 0, stream>>>(bv, bvf, D_MODEL, 1.f, flag);
    cvt_vec_f32<<<4, blk, 0, stream>>>(bo, bof, D_MODEL, 1.f, flag);
    cvt_vec_f32<<<16, blk, 0, stream>>>(b1, b1f, D_FF, 1.f, flag);
    cvt_vec_f32<<<4, blk, 0, stream>>>(b2, b2f, D_MODEL, 1.f, flag);
    cvt_vec_f32<<<4, blk, 0, stream>>>(alpha1, a1f, D_MODEL, 1.f, flag);
    cvt_vec_f32<<<4, blk, 0, stream>>>(bias1, be1f, D_MODEL, 1.f, flag);
    cvt_vec_f32<<<4, blk, 0, stream>>>(alpha2, a2f, D_MODEL, 1.f, flag);
    cvt_vec_f32<<<4, blk, 0, stream>>>(bias2, be2f, D_MODEL, 1.f, flag);

    transpose_to_bf16<<<dim3(16, 16), blk, 0, stream>>>(wq, wqT, D_MODEL, D_MODEL, 0.125f, flag);
    transpose_to_bf16<<<dim3(16, 16), blk, 0, stream>>>(wk, wkT, D_MODEL, D_MODEL, 1.f, flag);
    transpose_to_bf16<<<dim3(16, 16), blk, 0, stream>>>(wv, wvT, D_MODEL, D_MODEL, 1.f, flag);
    transpose_to_bf16<<<dim3(16, 16), blk, 0, stream>>>(wo, woT, D_MODEL, D_MODEL, 1.f, flag);
    transpose_to_bf16<<<dim3(64, 16), blk, 0, stream>>>(w1, w1T, D_MODEL, D_FF, 1.f, flag);
    transpose_to_bf16<<<dim3(16, 64), blk, 0, stream>>>(w2, w2T, D_FF, D_MODEL, 1.f, flag);

    ln_kernel<<<M_TOT, blk, 0, stream>>>(x, a1f, be1f, lnbuf, flag);

    gemm_bias_bf16<<<dim3(64, 8), blk, 0, stream>>>(lnbuf, wqT, bqf, qb,
                                                    M_TOT, D_MODEL, D_MODEL);
    gemm_bias_bf16<<<dim3(64, 8), blk, 0, stream>>>(lnbuf, wkT, bkf, kb,
                                                    M_TOT, D_MODEL, D_MODEL);
    gemm_bias_vt<<<dim3(64, 8), blk, 0, stream>>>(lnbuf, wvT, bvf, vtb,
                                                  M_TOT, D_MODEL, D_MODEL);

    attn_kernel<<<dim3(SEQ / 64, BATCH * N_HEADS), blk, 0, stream>>>(qb, kb, vtb, mask, attnb);

    gemm_bias_res_trunk<<<dim3(64, 8), blk, 0, stream>>>(attnb, woT, bof, x, trunk,
                                                         M_TOT, D_MODEL, D_MODEL, flag);

    ln_kernel<<<M_TOT, blk, 0, stream>>>(trunk, a2f, be2f, ln2buf, flagz);

    for (int qtr = 0; qtr < 4; qtr++) {
        const int off = qtr * 1024;
        gemm_relu_slice<<<dim3(64, 8), blk, 0, stream>>>(ln2buf, w1T, b1f, halfbuf,
                                                         M_TOT, 1024, D_MODEL, off);
        gemm_acc_slice<<<dim3(64, 8), blk, 0, stream>>>(halfbuf, w2T, b2f, trunk,
                                                        M_TOT, D_MODEL, 1024, off,
                                                        D_FF, qtr == 0 ? 1 : 0);
    }

    finalize_out<<<M_TOT * D_MODEL / 1024, blk, 0, stream>>>(trunk, d_out, flag);
}

// Round 7
// 716.549 us; speedup vs baseline: 1.2912x; 1.0909x over previous
//
#include <hip/hip_runtime.h>

#define D_MODEL 1024
#define D_FF    4096
#define N_HEADS 16
#define DK      64
#define BATCH   4
#define SEQ     2048
#define M_TOT   (BATCH*SEQ)   // 8192

typedef unsigned short ushort_t;
typedef __attribute__((ext_vector_type(8))) short  short8;
typedef __attribute__((ext_vector_type(4))) float  floatx4;

__device__ __forceinline__ float bf2f(ushort_t s) {
    return __uint_as_float(((unsigned int)s) << 16);
}
__device__ __forceinline__ ushort_t f2bf(float f) {
    unsigned int u = __float_as_uint(f);
    u += 0x7fff + ((u >> 16) & 1);   // round-to-nearest-even
    return (ushort_t)(u >> 16);
}
// async global->LDS, 16B per lane; LDS dest = wave-uniform base + lane*16
__device__ __forceinline__ void gll16(const void* g, void* l) {
    __builtin_amdgcn_global_load_lds(
        (const __attribute__((address_space(1))) void*)g,
        (__attribute__((address_space(3))) void*)l,
        16, 0, 0);
}

#if __has_builtin(__builtin_amdgcn_exp2f)
#define EXP2(x) __builtin_amdgcn_exp2f(x)
#else
#define EXP2(x) __expf((x) * 0.69314718055994531f)
#endif
#define L2E 1.4426950408889634f

// ---------------------------------------------------------------------------
// dtype detector (validated R5/R6)
// ---------------------------------------------------------------------------
__global__ void detect_dtype(const ushort_t* __restrict__ x, int* __restrict__ flag)
{
    const int t = threadIdx.x;
    int cnt = 0;
    for (int i = t; i < 512; i += 64) {
        ushort_t e = x[2 * i] & 0x7F80;
        cnt += (e >= 0x3800 && e <= 0x4380) ? 1 : 0;
    }
    for (int off = 32; off > 0; off >>= 1) cnt += __shfl_down(cnt, off, 64);
    if (t == 0) { flag[0] = (cnt >= 256) ? 1 : 0; flag[1] = 0; }
}

__global__ void cvt_vec_f32(const void* __restrict__ src, float* __restrict__ dst,
                            int n, float scale, const int* __restrict__ flag)
{
    const int i = blockIdx.x * 256 + threadIdx.x;
    if (i >= n) return;
    if (*flag) dst[i] = bf2f(((const ushort_t*)src)[i]) * scale;
    else       dst[i] = ((const float*)src)[i] * scale;
}

// ---------------------------------------------------------------------------
// weight transpose (+optional scale): in[K][N] -> out[N][K] bf16
// ---------------------------------------------------------------------------
__global__ __launch_bounds__(256) void transpose_to_bf16(
    const void* __restrict__ in, ushort_t* __restrict__ out, int K, int N,
    float scale, const int* __restrict__ flag)
{
    __shared__ ushort_t tile[64 * 72];
    const int n0 = blockIdx.x * 64, k0 = blockIdx.y * 64;
    const int t = threadIdx.x, sr = t >> 2, sc = (t & 3) * 16;
    const long g = (long)(k0 + sr) * N + n0 + sc;
    ushort_t cv[16];
    if (*flag) {
        const ushort_t* p = (const ushort_t*)in;
        #pragma unroll
        for (int j = 0; j < 16; j++) cv[j] = f2bf(bf2f(p[g + j]) * scale);
    } else {
        const float* p = (const float*)in;
        #pragma unroll
        for (int j = 0; j < 16; j += 4) {
            float4 fv = *(const float4*)&p[g + j];
            cv[j] = f2bf(fv.x * scale); cv[j+1] = f2bf(fv.y * scale);
            cv[j+2] = f2bf(fv.z * scale); cv[j+3] = f2bf(fv.w * scale);
        }
    }
    #pragma unroll
    for (int j = 0; j < 16; j++) tile[sr * 72 + sc + j] = cv[j];
    __syncthreads();
    __attribute__((aligned(16))) ushort_t tmp[16];
    #pragma unroll
    for (int j = 0; j < 16; j++) tmp[j] = tile[(sc + j) * 72 + sr];
    const long go = (long)(n0 + sr) * K + k0 + sc;
    *(int4*)&out[go]     = *(const int4*)&tmp[0];
    *(int4*)&out[go + 8] = *(const int4*)&tmp[8];
}

// ---------------------------------------------------------------------------
// Tensor1DNorm (validated)
// ---------------------------------------------------------------------------
__global__ __launch_bounds__(256) void ln_kernel(
    const void* __restrict__ xraw, const float* __restrict__ alpha,
    const float* __restrict__ beta, ushort_t* __restrict__ out,
    const int* __restrict__ flag)
{
    __shared__ float red[8];
    __shared__ float stats[2];
    const int row = blockIdx.x, t = threadIdx.x;
    const long idx = (long)row * D_MODEL + t * 4;
    float v0, v1, v2, v3;
    if (*flag) {
        ushort4 u = *(const ushort4*)&((const ushort_t*)xraw)[idx];
        v0 = bf2f(u.x); v1 = bf2f(u.y); v2 = bf2f(u.z); v3 = bf2f(u.w);
    } else {
        float4 fv = *(const float4*)&((const float*)xraw)[idx];
        v0 = fv.x; v1 = fv.y; v2 = fv.z; v3 = fv.w;
    }
    float s  = v0 + v1 + v2 + v3;
    float s2 = v0 * v0 + v1 * v1 + v2 * v2 + v3 * v3;
    for (int off = 32; off > 0; off >>= 1) {
        s  += __shfl_down(s,  off, 64);
        s2 += __shfl_down(s2, off, 64);
    }
    const int w = t >> 6, lane = t & 63;
    if (lane == 0) { red[w] = s; red[4 + w] = s2; }
    __syncthreads();
    if (t == 0) {
        float S  = red[0] + red[1] + red[2] + red[3];
        float S2 = red[4] + red[5] + red[6] + red[7];
        float mean = S / D_MODEL;
        float var  = fmaxf((S2 - mean * S) / (D_MODEL - 1), 0.f);
        stats[0] = mean;
        stats[1] = 1.f / (sqrtf(var) + 1e-6f);
    }
    __syncthreads();
    const float mean = stats[0], inv = stats[1];
    float vv[4] = {v0, v1, v2, v3};
    ushort4 o;
    ushort_t* op = (ushort_t*)&o;
    #pragma unroll
    for (int j = 0; j < 4; j++)
        op[j] = f2bf(alpha[t * 4 + j] * (vv[j] - mean) * inv + beta[t * 4 + j]);
    *(ushort4*)&out[idx] = o;
}

// ---------------------------------------------------------------------------
// GEMM core: 128x128 tile, BK=32, global_load_lds(16B) staging (validated)
// ---------------------------------------------------------------------------
#define GEMM_PROLOG()                                                         \
    __shared__ ushort_t As[128 * 32];                                         \
    __shared__ ushort_t Bs[128 * 32];                                         \
    const int m0 = blockIdx.x * 128, n0 = blockIdx.y * 128;                   \
    const int t = threadIdx.x;                                                \
    const int w = t >> 6, lane = t & 63, quad = lane >> 4, l15 = lane & 15;   \
    const int wm = (w >> 1) * 64, wn = (w & 1) * 64;                          \
    floatx4 acc[4][4] = {};

#define GEMM_KLOOP(Abase, LDA, Bbase, LDB, KLEN)                              \
    {                                                                         \
    const ushort_t* gA = (Abase) + (long)(m0 + w * 32 + (lane >> 2)) * (LDA)  \
                         + (lane & 3) * 8;                                    \
    const ushort_t* gB = (Bbase) + (long)(n0 + w * 32 + (lane >> 2)) * (LDB)  \
                         + (lane & 3) * 8;                                    \
    for (int k0 = 0; k0 < (KLEN); k0 += 32) {                                 \
        gll16(gA + k0,                     &As[(w * 32) * 32]);               \
        gll16(gA + k0 + 16 * (long)(LDA), &As[(w * 32 + 16) * 32]);           \
        gll16(gB + k0,                     &Bs[(w * 32) * 32]);               \
        gll16(gB + k0 + 16 * (long)(LDB), &Bs[(w * 32 + 16) * 32]);           \
        __syncthreads();                                                      \
        short8 af[4], bf[4];                                                  \
        _Pragma("unroll")                                                     \
        for (int i = 0; i < 4; i++)                                           \
            af[i] = *(const short8*)&As[(wm + i * 16 + l15) * 32 + quad * 8]; \
        _Pragma("unroll")                                                     \
        for (int j = 0; j < 4; j++)                                           \
            bf[j] = *(const short8*)&Bs[(wn + j * 16 + l15) * 32 + quad * 8]; \
        _Pragma("unroll")                                                     \
        for (int i = 0; i < 4; i++) {                                         \
            _Pragma("unroll")                                                 \
            for (int j = 0; j < 4; j++)                                       \
                acc[i][j] = __builtin_amdgcn_mfma_f32_16x16x32_bf16(          \
                    af[i], bf[j], acc[i][j], 0, 0, 0);                        \
        }                                                                     \
        __syncthreads();                                                      \
    }                                                                         \
    }

// Fused QKV: BT = wqkvT [3072][1024]; epilogue routes per 1024-segment.
// seg0 -> qb [M][1024]; seg1 -> kb; seg2 -> vt [B][H][DK][S].
__global__ __launch_bounds__(256) void gemm_qkv(
    const ushort_t* __restrict__ A, const ushort_t* __restrict__ BT,
    const float* __restrict__ bias, ushort_t* __restrict__ qb,
    ushort_t* __restrict__ kb, ushort_t* __restrict__ vtb, int M, int K)
{
    GEMM_PROLOG();
    GEMM_KLOOP(A, K, BT, K, K);
    const int nbase = n0 + wn;          // multiple of 64; wave-uniform segment
    const int seg = nbase >> 10;
    #pragma unroll
    for (int j = 0; j < 4; j++) {
        const int ng = nbase + j * 16 + l15;
        const float bv = bias[ng];
        const int nl = ng & 1023;
        #pragma unroll
        for (int i = 0; i < 4; i++) {
            const int mb_ = m0 + wm + i * 16 + quad * 4;
            if (seg == 2) {
                ushort4 pv;
                #pragma unroll
                for (int r = 0; r < 4; r++)
                    ((ushort_t*)&pv)[r] = f2bf(acc[i][j][r] + bv);
                const long idx = ((long)(mb_ >> 11) * 1024 + nl) * 2048 + (mb_ & 2047);
                *(ushort4*)&vtb[idx] = pv;
            } else {
                ushort_t* dst = seg ? kb : qb;
                #pragma unroll
                for (int r = 0; r < 4; r++)
                    dst[(long)(mb_ + r) * 1024 + nl] = f2bf(acc[i][j][r] + bv);
            }
        }
    }
}

// O-proj: trunk fp32 = A @ BT^T + bias + raw-x residual (flag-typed)
__global__ __launch_bounds__(256) void gemm_bias_res_trunk(
    const ushort_t* __restrict__ A, const ushort_t* __restrict__ BT,
    const float* __restrict__ bias, const void* __restrict__ res,
    float* __restrict__ C, int M, int N, int K, const int* __restrict__ flag)
{
    GEMM_PROLOG();
    const int fl = *flag;
    GEMM_KLOOP(A, K, BT, K, K);
    #pragma unroll
    for (int j = 0; j < 4; j++) {
        const int n = n0 + wn + j * 16 + l15;
        const float bv = bias[n];
        #pragma unroll
        for (int i = 0; i < 4; i++) {
            const int mbase = m0 + wm + i * 16 + quad * 4;
            #pragma unroll
            for (int r = 0; r < 4; r++) {
                const long idx = (long)(mbase + r) * N + n;
                const float rv = fl ? bf2f(((const ushort_t*)res)[idx])
                                    : ((const float*)res)[idx];
                C[idx] = acc[i][j][r] + bv + rv;
            }
        }
    }
}

// FF1 slice: C[M][Nc] bf16 = relu(A @ BT[noff..]^T + bias[noff..])
__global__ __launch_bounds__(256) void gemm_relu_slice(
    const ushort_t* __restrict__ A, const ushort_t* __restrict__ BT,
    const float* __restrict__ bias, ushort_t* __restrict__ C,
    int M, int Nc, int K, int noff)
{
    GEMM_PROLOG();
    const ushort_t* BTo = BT + (long)noff * K;
    GEMM_KLOOP(A, K, BTo, K, K);
    #pragma unroll
    for (int j = 0; j < 4; j++) {
        const int n = n0 + wn + j * 16 + l15;
        const float bv = bias[noff + n];
        #pragma unroll
        for (int i = 0; i < 4; i++) {
            const int mbase = m0 + wm + i * 16 + quad * 4;
            #pragma unroll
            for (int r = 0; r < 4; r++)
                C[(long)(mbase + r) * Nc + n] = f2bf(fmaxf(acc[i][j][r] + bv, 0.f));
        }
    }
}

// FF2 slice accumulate into fp32 trunk (pass0: += bias; trunk holds residual)
__global__ __launch_bounds__(256) void gemm_acc_slice(
    const ushort_t* __restrict__ A, const ushort_t* __restrict__ BT,
    const float* __restrict__ bias, float* __restrict__ C,
    int M, int N, int Kc, int koff, int Kfull, int pass0)
{
    GEMM_PROLOG();
    const ushort_t* BTo = BT + koff;
    GEMM_KLOOP(A, Kc, BTo, Kfull, Kc);
    #pragma unroll
    for (int j = 0; j < 4; j++) {
        const int n = n0 + wn + j * 16 + l15;
        const float bv = pass0 ? bias[n] : 0.f;
        #pragma unroll
        for (int i = 0; i < 4; i++) {
            const int mbase = m0 + wm + i * 16 + quad * 4;
            #pragma unroll
            for (int r = 0; r < 4; r++) {
                const long idx = (long)(mbase + r) * N + n;
                C[idx] = C[idx] + bv + acc[i][j][r];
            }
        }
    }
}

// FF2 final slice: out (per flag dtype) = Cin + A @ BTslice^T
__global__ __launch_bounds__(256) void gemm_acc_final(
    const ushort_t* __restrict__ A, const ushort_t* __restrict__ BT,
    const float* __restrict__ Cin, void* __restrict__ out,
    int M, int N, int Kc, int koff, int Kfull, const int* __restrict__ flag)
{
    GEMM_PROLOG();
    const int fl = *flag;
    const ushort_t* BTo = BT + koff;
    GEMM_KLOOP(A, Kc, BTo, Kfull, Kc);
    #pragma unroll
    for (int j = 0; j < 4; j++) {
        const int n = n0 + wn + j * 16 + l15;
        #pragma unroll
        for (int i = 0; i < 4; i++) {
            const int mbase = m0 + wm + i * 16 + quad * 4;
            #pragma unroll
            for (int r = 0; r < 4; r++) {
                const long idx = (long)(mbase + r) * N + n;
                const float v = Cin[idx] + acc[i][j][r];
                if (fl) ((ushort_t*)out)[idx] = f2bf(v);
                else    ((float*)out)[idx] = v;
            }
        }
    }
}

__global__ __launch_bounds__(256) void finalize_out(
    const float* __restrict__ trunk, void* __restrict__ out,
    const int* __restrict__ flag)
{
    const long i = ((long)blockIdx.x * 256 + threadIdx.x) * 4;
    float4 tv = *(const float4*)&trunk[i];
    if (*flag) {
        ushort4 o = { f2bf(tv.x), f2bf(tv.y), f2bf(tv.z), f2bf(tv.w) };
        *(ushort4*)&((ushort_t*)out)[i] = o;
    } else {
        *(float4*)&((float*)out)[i] = tv;
    }
}

// ---------------------------------------------------------------------------
// Flash attention v3: S^T formulation + VALU diet.
// max over RAW scores (upper bound is valid); p = exp2(fma(s,L2E,mbL-mnL));
// P packed by truncation via v_perm (2 values/op).
// ---------------------------------------------------------------------------
__global__ __launch_bounds__(256) void attn_kernel(
    const ushort_t* __restrict__ q, const ushort_t* __restrict__ k,
    const ushort_t* __restrict__ vt, const int* __restrict__ mask,
    ushort_t* __restrict__ out)
{
    __shared__ ushort_t Qs[64 * 72];
    __shared__ ushort_t Ks[64 * 72];
    __shared__ ushort_t Vs[64 * 72];
    __shared__ ushort_t Ps[64 * 72];
    __shared__ float MbL[64];
    __shared__ float Asm[64];
    __shared__ float Lsm[64];
    const int qt = blockIdx.x, bh = blockIdx.y;
    const int b = bh >> 4, h = bh & 15;
    const int t = threadIdx.x, w = t >> 6, lane = t & 63;
    const int quad = lane >> 4, l15 = lane & 15;
    const int sr = t >> 2, sc = (t & 3) * 16;
    const int q0 = qt * 64;
    const long rowbase = (long)b * SEQ * D_MODEL + (long)h * DK;
    const long vtbase  = ((long)(b * 16 + h) * DK) * SEQ;
    {
        const long g = rowbase + (long)(q0 + sr) * D_MODEL + sc;
        *(int4*)&Qs[sr * 72 + sc]     = *(const int4*)&q[g];
        *(int4*)&Qs[sr * 72 + sc + 8] = *(const int4*)&q[g + 8];
    }
    floatx4 o[4] = {};
    float m2 = -3.0e30f, lrow = 0.f;   // m2 = running max in log2 units

    for (int kt = 0; kt < SEQ / 64; kt++) {
        {
            const long gk = rowbase + (long)(kt * 64 + sr) * D_MODEL + sc;
            *(int4*)&Ks[sr * 72 + sc]     = *(const int4*)&k[gk];
            *(int4*)&Ks[sr * 72 + sc + 8] = *(const int4*)&k[gk + 8];
            const long gv = vtbase + (long)sr * SEQ + kt * 64 + sc;
            *(int4*)&Vs[sr * 72 + sc]     = *(const int4*)&vt[gv];
            *(int4*)&Vs[sr * 72 + sc + 8] = *(const int4*)&vt[gv + 8];
        }
        if (t < 64)
            MbL[t] = (mask[b * SEQ + kt * 64 + t] == 0) ? -1.442695e9f : 0.0f;
        __syncthreads();

        // S^T = K·Q^T  (q pre-scaled by 1/8)
        floatx4 s[4] = {};
        #pragma unroll
        for (int ks = 0; ks < 2; ks++) {
            short8 bq = *(const short8*)&Qs[(w * 16 + l15) * 72 + ks * 32 + quad * 8];
            #pragma unroll
            for (int nt = 0; nt < 4; nt++) {
                short8 ak = *(const short8*)&Ks[(nt * 16 + l15) * 72 + ks * 32 + quad * 8];
                s[nt] = __builtin_amdgcn_mfma_f32_16x16x32_bf16(ak, bq, s[nt], 0, 0, 0);
            }
        }
        // per-q max over RAW scores (upper bound; masked cols underflow to 0)
        float tmax = -1e30f;
        #pragma unroll
        for (int nt = 0; nt < 4; nt++) {
            #pragma unroll
            for (int r = 0; r < 4; r++) tmax = fmaxf(tmax, s[nt][r]);
        }
        tmax = fmaxf(tmax, __shfl_xor(tmax, 16, 64));
        tmax = fmaxf(tmax, __shfl_xor(tmax, 32, 64));
        const float mnL = fmaxf(m2, tmax * L2E);
        const float al = EXP2(m2 - mnL);
        m2 = mnL;
        float sum = 0.f;
        #pragma unroll
        for (int nt = 0; nt < 4; nt++) {
            float4 mb4 = *(const float4*)&MbL[nt * 16 + quad * 4];
            float p[4];
            #pragma unroll
            for (int r = 0; r < 4; r++) {
                p[r] = EXP2(fmaf(s[nt][r], L2E, ((const float*)&mb4)[r] - mnL));
                sum += p[r];
            }
            uint2 pk;
            pk.x = __builtin_amdgcn_perm(__float_as_uint(p[1]), __float_as_uint(p[0]), 0x07060302u);
            pk.y = __builtin_amdgcn_perm(__float_as_uint(p[3]), __float_as_uint(p[2]), 0x07060302u);
            *(uint2*)&Ps[(w * 16 + l15) * 72 + nt * 16 + quad * 4] = pk;
        }
        sum += __shfl_xor(sum, 16, 64);
        sum += __shfl_xor(sum, 32, 64);
        lrow = lrow * al + sum;
        // broadcast alpha from q=l15 lanes to q=quad*4+r accumulator layout
        Asm[w * 16 + l15] = al;
        float4 al4 = *(const float4*)&Asm[w * 16 + quad * 4];
        const float* alp = (const float*)&al4;
        #pragma unroll
        for (int j = 0; j < 4; j++) {
            #pragma unroll
            for (int r = 0; r < 4; r++) o[j][r] *= alp[r];
        }
        // O += P·V
        #pragma unroll
        for (int ks = 0; ks < 2; ks++) {
            short8 ap = *(const short8*)&Ps[(w * 16 + l15) * 72 + ks * 32 + quad * 8];
            #pragma unroll
            for (int j = 0; j < 4; j++) {
                short8 bv = *(const short8*)&Vs[(j * 16 + l15) * 72 + ks * 32 + quad * 8];
                o[j] = __builtin_amdgcn_mfma_f32_16x16x32_bf16(ap, bv, o[j], 0, 0, 0);
            }
        }
        __syncthreads();
    }
    Lsm[w * 16 + l15] = lrow;
    float4 lr4 = *(const float4*)&Lsm[w * 16 + quad * 4];
    float inv[4];
    #pragma unroll
    for (int r = 0; r < 4; r++) inv[r] = 1.f / ((const float*)&lr4)[r];
    #pragma unroll
    for (int j = 0; j < 4; j++) {
        const int d = j * 16 + l15;
        #pragma unroll
        for (int r = 0; r < 4; r++) {
            const int row = q0 + w * 16 + quad * 4 + r;
            out[rowbase + (long)row * D_MODEL + d] = f2bf(o[j][r] * inv[r]);
        }
    }
}

// ---------------------------------------------------------------------------
// Launch. Common: 0-6 wqkvT, 6-8 woT, 8-16 w1T, 16-24 w2T, 24-25 params,
// 25-41 lnbuf/attnb, 41-57 qb, 57-73 kb, 73-89 vtb.
// Path A (ws>=121MB): trunk fp32 57-89, ln2buf 41-57, halfbuf 89-121, FF halves.
// Path B: R6-proven quarters (trunk 41-73, ln2buf 73-89, halfbuf 25-41).
// ---------------------------------------------------------------------------
extern "C" void kernel_launch(void* const* d_in, const int* in_sizes, int n_in,
                              void* d_out, int out_size, void* d_ws, size_t ws_size,
                              hipStream_t stream)
{
    const void* x      = d_in[0];
    const int*  mask   = (const int*)d_in[1];
    const void* wq     = d_in[2];
    const void* bq     = d_in[3];
    const void* wk     = d_in[4];
    const void* bk     = d_in[5];
    const void* wv     = d_in[6];
    const void* bv     = d_in[7];
    const void* wo     = d_in[8];
    const void* bo     = d_in[9];
    const void* w1     = d_in[10];
    const void* b1     = d_in[11];
    const void* w2     = d_in[12];
    const void* b2     = d_in[13];
    const void* alpha1 = d_in[14];
    const void* bias1  = d_in[15];
    const void* alpha2 = d_in[16];
    const void* bias2  = d_in[17];

    char* ws = (char*)d_ws;
    const size_t MB = 1024 * 1024;
    const size_t KB = 1024;
    ushort_t* wqkvT = (ushort_t*)(ws + 0 * MB);   // [3072][1024] bf16
    ushort_t* woT   = (ushort_t*)(ws + 6 * MB);
    ushort_t* w1T   = (ushort_t*)(ws + 8 * MB);
    ushort_t* w2T   = (ushort_t*)(ws + 16 * MB);
    float* bqkvf = (float*)(ws + 24 * MB + 0 * 16 * KB);  // 3072 floats
    float* bof   = (float*)(ws + 24 * MB + 1 * 16 * KB);
    float* b1f   = (float*)(ws + 24 * MB + 2 * 16 * KB);  // 4096 floats
    float* b2f   = (float*)(ws + 24 * MB + 3 * 16 * KB);
    float* a1f   = (float*)(ws + 24 * MB + 4 * 16 * KB);
    float* be1f  = (float*)(ws + 24 * MB + 5 * 16 * KB);
    float* a2f   = (float*)(ws + 24 * MB + 6 * 16 * KB);
    float* be2f  = (float*)(ws + 24 * MB + 7 * 16 * KB);
    int*   flag  = (int*)(ws + 24 * MB + 8 * 16 * KB);
    int*   flagz = flag + 1;
    ushort_t* lnbuf = (ushort_t*)(ws + 25 * MB);
    ushort_t* qb    = (ushort_t*)(ws + 41 * MB);
    ushort_t* kb    = (ushort_t*)(ws + 57 * MB);
    ushort_t* vtb   = (ushort_t*)(ws + 73 * MB);
    ushort_t* attnb = lnbuf;

    const bool bigws = (ws_size >= 121ull * MB);

    dim3 blk(256);
    detect_dtype<<<1, 64, 0, stream>>>((const ushort_t*)x, flag);

    cvt_vec_f32<<<4, blk, 0, stream>>>(bq, bqkvf + 0, D_MODEL, 0.125f, flag);
    cvt_vec_f32<<<4, blk, 0, stream>>>(bk, bqkvf + 1024, D_MODEL, 1.f, flag);
    cvt_vec_f32<<<4, blk, 0, stream>>>(bv, bqkvf + 2048, D_MODEL, 1.f, flag);
    cvt_vec_f32<<<4, blk, 0, stream>>>(bo, bof, D_MODEL, 1.f, flag);
    cvt_vec_f32<<<16, blk, 0, stream>>>(b1, b1f, D_FF, 1.f, flag);
    cvt_vec_f32<<<4, blk, 0, stream>>>(b2, b2f, D_MODEL, 1.f, flag);
    cvt_vec_f32<<<4, blk, 0, stream>>>(alpha1, a1f, D_MODEL, 1.f, flag);
    cvt_vec_f32<<<4, blk, 0, stream>>>(bias1, be1f, D_MODEL, 1.f, flag);
    cvt_vec_f32<<<4, blk, 0, stream>>>(alpha2, a2f, D_MODEL, 1.f, flag);
    cvt_vec_f32<<<4, blk, 0, stream>>>(bias2, be2f, D_MODEL, 1.f, flag);

    transpose_to_bf16<<<dim3(16, 16), blk, 0, stream>>>(wq, wqkvT, D_MODEL, D_MODEL, 0.125f, flag);
    transpose_to_bf16<<<dim3(16, 16), blk, 0, stream>>>(wk, wqkvT + 1024 * 1024, D_MODEL, D_MODEL, 1.f, flag);
    transpose_to_bf16<<<dim3(16, 16), blk, 0, stream>>>(wv, wqkvT + 2048 * 1024, D_MODEL, D_MODEL, 1.f, flag);
    transpose_to_bf16<<<dim3(16, 16), blk, 0, stream>>>(wo, woT, D_MODEL, D_MODEL, 1.f, flag);
    transpose_to_bf16<<<dim3(64, 16), blk, 0, stream>>>(w1, w1T, D_MODEL, D_FF, 1.f, flag);
    transpose_to_bf16<<<dim3(16, 64), blk, 0, stream>>>(w2, w2T, D_FF, D_MODEL, 1.f, flag);

    ln_kernel<<<M_TOT, blk, 0, stream>>>(x, a1f, be1f, lnbuf, flag);

    gemm_qkv<<<dim3(64, 24), blk, 0, stream>>>(lnbuf, wqkvT, bqkvf, qb, kb, vtb,
                                               M_TOT, D_MODEL);

    attn_kernel<<<dim3(SEQ / 64, BATCH * N_HEADS), blk, 0, stream>>>(qb, kb, vtb, mask, attnb);

    if (bigws) {
        float*    trunk   = (float*)kb;                 // 57-89 MB (32 MB fp32)
        ushort_t* ln2buf  = qb;                         // 41-57
        ushort_t* halfbuf = (ushort_t*)(ws + 89 * MB);  // 89-121 (32 MB bf16)
        gemm_bias_res_trunk<<<dim3(64, 8), blk, 0, stream>>>(attnb, woT, bof, x, trunk,
                                                             M_TOT, D_MODEL, D_MODEL, flag);
        ln_kernel<<<M_TOT, blk, 0, stream>>>(trunk, a2f, be2f, ln2buf, flagz);
        gemm_relu_slice<<<dim3(64, 16), blk, 0, stream>>>(ln2buf, w1T, b1f, halfbuf,
                                                          M_TOT, 2048, D_MODEL, 0);
        gemm_acc_slice<<<dim3(64, 8), blk, 0, stream>>>(halfbuf, w2T, b2f, trunk,
                                                        M_TOT, D_MODEL, 2048, 0, D_FF, 1);
        gemm_relu_slice<<<dim3(64, 16), blk, 0, stream>>>(ln2buf, w1T, b1f, halfbuf,
                                                          M_TOT, 2048, D_MODEL, 2048);
        gemm_acc_final<<<dim3(64, 8), blk, 0, stream>>>(halfbuf, w2T, trunk, d_out,
                                                        M_TOT, D_MODEL, 2048, 2048, D_FF, flag);
    } else {
        float*    trunk   = (float*)qb;    // 41-73 (32 MB fp32), R6-proven
        ushort_t* ln2buf  = vtb;           // 73-89
        ushort_t* halfbuf = lnbuf;         // 25-41 (16 MB)
        gemm_bias_res_trunk<<<dim3(64, 8), blk, 0, stream>>>(attnb, woT, bof, x, trunk,
                                                             M_TOT, D_MODEL, D_MODEL, flag);
        ln_kernel<<<M_TOT, blk, 0, stream>>>(trunk, a2f, be2f, ln2buf, flagz);
        for (int qtr = 0; qtr < 4; qtr++) {
            const int off = qtr * 1024;
            gemm_relu_slice<<<dim3(64, 8), blk, 0, stream>>>(ln2buf, w1T, b1f, halfbuf,
                                                             M_TOT, 1024, D_MODEL, off);
            gemm_acc_slice<<<dim3(64, 8), blk, 0, stream>>>(halfbuf, w2T, b2f, trunk,
                                                            M_TOT, D_MODEL, 1024, off,
                                                            D_FF, qtr == 0 ? 1 : 0);
        }
        finalize_out<<<M_TOT * D_MODEL / 1024, blk, 0, stream>>>(trunk, d_out, flag);
    }
}